// Round 1
// baseline (551.328 us; speedup 1.0000x reference)
//
#include <hip/hip_runtime.h>

// Holt double-exponential smoothing, faithful to the reference's quirky init:
//   out[0] = 0
//   out[1] = x[1]           (state NOT updated at t=1)
//   t>=2:  s = a*x + (1-a)*(s_prev + b_prev);  out[t] = s
//          b = B*(s - s_prev) + (1-B)*b_prev
// with s_prev = b_prev = 0 entering t=2.  ALPHA = BETA = 0.5.
//
// Mapping: one thread per (b,n) sequence; T=1024 contiguous floats per
// sequence; float4 loads/stores; 8x unroll so the compiler batches 8
// independent global_load_dwordx4 per thread for latency hiding.
// Cache-line reuse: lanes are 4KB apart, so each load instruction touches
// 64 distinct 128B lines; the 8 consecutive float4 groups per lane reuse
// each line from L1/L2 (read working set = 8KB/wave = 32KB/CU).

constexpr int T_STEPS = 1024;
constexpr int GROUPS  = T_STEPS / 4;  // 256 float4 groups per sequence

__global__ __launch_bounds__(256)
void holt_filter_kernel(const float* __restrict__ x, float* __restrict__ out,
                        int nseq) {
    int seq = blockIdx.x * blockDim.x + threadIdx.x;
    if (seq >= nseq) return;

    const float4* __restrict__ xv =
        reinterpret_cast<const float4*>(x + (size_t)seq * T_STEPS);
    float4* __restrict__ ov =
        reinterpret_cast<float4*>(out + (size_t)seq * T_STEPS);

    float s = 0.0f, b = 0.0f;

    // Group 0: t = 0..3 (special init for t=0, t=1).
    {
        float4 v = xv[0];
        float4 o;
        o.x = 0.0f;   // t=0: zero init state
        o.y = v.y;    // t=1: s = x1, but carry state stays (0,0)
        // t=2
        float sn = 0.5f * v.z + 0.5f * (s + b);
        b = 0.5f * (sn - s) + 0.5f * b;
        s = sn; o.z = sn;
        // t=3
        sn = 0.5f * v.w + 0.5f * (s + b);
        b = 0.5f * (sn - s) + 0.5f * b;
        s = sn; o.w = sn;
        ov[0] = o;
    }

#pragma unroll 8
    for (int g = 1; g < GROUPS; ++g) {
        float4 v = xv[g];
        float4 o;
        float sn;
        sn = 0.5f * v.x + 0.5f * (s + b);
        b = 0.5f * (sn - s) + 0.5f * b; s = sn; o.x = sn;
        sn = 0.5f * v.y + 0.5f * (s + b);
        b = 0.5f * (sn - s) + 0.5f * b; s = sn; o.y = sn;
        sn = 0.5f * v.z + 0.5f * (s + b);
        b = 0.5f * (sn - s) + 0.5f * b; s = sn; o.z = sn;
        sn = 0.5f * v.w + 0.5f * (s + b);
        b = 0.5f * (sn - s) + 0.5f * b; s = sn; o.w = sn;
        ov[g] = o;
    }
}

extern "C" void kernel_launch(void* const* d_in, const int* in_sizes, int n_in,
                              void* d_out, int out_size, void* d_ws, size_t ws_size,
                              hipStream_t stream) {
    const float* x = (const float*)d_in[0];
    float* out = (float*)d_out;

    const int nseq = in_sizes[0] / T_STEPS;  // 32 * 2048 = 65536
    const int block = 256;
    const int grid = (nseq + block - 1) / block;

    holt_filter_kernel<<<grid, block, 0, stream>>>(x, out, nseq);
}

// Round 2
// 505.631 us; speedup vs baseline: 1.0904x; 1.0904x over previous
//
#include <hip/hip_runtime.h>

// Holt double-exponential smoothing, chunk-parallel decomposition.
//
// Recurrence (t>=2): s = 0.5*x + 0.5*(s_p + b_p); b = 0.5*(s - s_p) + 0.5*b_p
// is affine: state_t = A * state_{t-1} + (0.5 x, 0.25 x),
//   A = [[0.5, 0.5], [-0.25, 0.75]], |eigenvalues| = sqrt(0.5).
// Split each T=1024 sequence into C=16 chunks of L=64:
//   Phase A: per-chunk zero-init run (x held in registers) -> chunk-final state
//   Phase B: block-local serial scan over chunks with constant A^64
//            (||A^64|| ~ 1.6e-10, so composition rounding is sub-ulp)
//   Phase C: exact sequential recurrence from corrected init; store outputs.
// Quirky init (faithful to reference): out[0]=0; out[1]=x[1] with NO state
// update; state entering t=2 is (0,0).
//
// Round-1 lesson: 1 wave/SIMD (Occupancy 11%) was latency-bound at 2.1 TB/s.
// This gives 16x the waves (4096 blocks x 256 thr) at ~4 waves/SIMD.

constexpr int T_STEPS = 1024;
constexpr int CHUNKS  = 16;            // chunks per sequence
constexpr int CLEN    = T_STEPS / CHUNKS;  // 64 steps per chunk
constexpr int CGROUPS = CLEN / 4;      // 16 float4 groups per chunk
constexpr int SEQ_PER_BLOCK = 256 / CHUNKS; // 16 sequences per block

// Compile-time A^64 in double precision.
struct Md { double a00, a01, a10, a11; };
constexpr Md apow(int n) {
    Md p{1.0, 0.0, 0.0, 1.0};
    const Md A{0.5, 0.5, -0.25, 0.75};
    for (int i = 0; i < n; ++i) {
        Md q{A.a00 * p.a00 + A.a01 * p.a10,
             A.a00 * p.a01 + A.a01 * p.a11,
             A.a10 * p.a00 + A.a11 * p.a10,
             A.a10 * p.a01 + A.a11 * p.a11};
        p = q;
    }
    return p;
}
constexpr Md P64 = apow(64);

__global__ __launch_bounds__(256)
void holt_chunked_kernel(const float* __restrict__ x, float* __restrict__ out) {
    const int tid   = threadIdx.x;
    const int chunk = tid & (CHUNKS - 1);
    const int sloc  = tid >> 4;  // local sequence index, 0..15
    const size_t seq = (size_t)blockIdx.x * SEQ_PER_BLOCK + sloc;
    const size_t base = seq * T_STEPS + (size_t)chunk * CLEN;

    const float4* __restrict__ xv = reinterpret_cast<const float4*>(x + base);
    float4* __restrict__ ov = reinterpret_cast<float4*>(out + base);

    // Load the whole chunk into registers (16 float4 = 64 VGPRs).
    float4 v[CGROUPS];
#pragma unroll
    for (int g = 0; g < CGROUPS; ++g) v[g] = xv[g];

    float s = 0.0f, b = 0.0f;
    auto step = [&](float xval) {
        float sn = 0.5f * xval + 0.5f * (s + b);
        b = 0.5f * (sn - s) + 0.5f * b;
        s = sn;
    };

    // ---- Phase A: zero-init run, final state only ----
    if (chunk == 0) {
        // t=0: no update; t=1: no state update (quirky init); t=2,3: normal.
        step(v[0].z); step(v[0].w);
    } else {
        step(v[0].x); step(v[0].y); step(v[0].z); step(v[0].w);
    }
#pragma unroll
    for (int g = 1; g < CGROUPS; ++g) {
        step(v[g].x); step(v[g].y); step(v[g].z); step(v[g].w);
    }

    __shared__ float lS[256];
    __shared__ float lB[256];
    lS[tid] = s;
    lB[tid] = b;
    __syncthreads();

    // ---- Phase B: per-sequence scan over chunk states (16 threads active) ----
    if (tid < SEQ_PER_BLOCK) {
        const int o = tid * CHUNKS;
        const float p00 = (float)P64.a00, p01 = (float)P64.a01;
        const float p10 = (float)P64.a10, p11 = (float)P64.a11;
        float ts = lS[o], tb = lB[o];  // true state after chunk 0
        lS[o] = 0.0f; lB[o] = 0.0f;    // init for chunk 0
        for (int j = 1; j < CHUNKS; ++j) {
            float us = lS[o + j], ub = lB[o + j];
            lS[o + j] = ts;  lB[o + j] = tb;   // init state for chunk j
            float ns = us + p00 * ts + p01 * tb;
            float nb = ub + p10 * ts + p11 * tb;
            ts = ns; tb = nb;
        }
    }
    __syncthreads();

    // ---- Phase C: exact recurrence from corrected init; store outputs ----
    s = lS[sloc * CHUNKS + chunk];
    b = lB[sloc * CHUNKS + chunk];

    {
        float4 o0;
        if (chunk == 0) {
            o0.x = 0.0f;      // t=0
            o0.y = v[0].y;    // t=1 (state not updated)
            step(v[0].z); o0.z = s;
            step(v[0].w); o0.w = s;
        } else {
            step(v[0].x); o0.x = s;
            step(v[0].y); o0.y = s;
            step(v[0].z); o0.z = s;
            step(v[0].w); o0.w = s;
        }
        ov[0] = o0;
    }
#pragma unroll
    for (int g = 1; g < CGROUPS; ++g) {
        float4 o;
        step(v[g].x); o.x = s;
        step(v[g].y); o.y = s;
        step(v[g].z); o.z = s;
        step(v[g].w); o.w = s;
        ov[g] = o;
    }
}

extern "C" void kernel_launch(void* const* d_in, const int* in_sizes, int n_in,
                              void* d_out, int out_size, void* d_ws, size_t ws_size,
                              hipStream_t stream) {
    const float* x = (const float*)d_in[0];
    float* out = (float*)d_out;

    const int nseq = in_sizes[0] / T_STEPS;          // 65536
    const int grid = nseq / SEQ_PER_BLOCK;           // 4096 blocks

    holt_chunked_kernel<<<grid, 256, 0, stream>>>(x, out);
}